// Round 5
// baseline (180.162 us; speedup 1.0000x reference)
//
#include <hip/hip_runtime.h>
#include <math.h>

// MAM dense: C[m,n] = max_k(A[m,k]*W[n,k]) + min_k(A[m,k]*W[n,k]) + bias[n]
// A: [M,K] fp32, W: [N,K] fp32 (torch layout), C: [M,N]
//
// R5: occupancy fix (R3 theory) with R2-proven asm form. R2 had 512 blocks =
// 2 waves/SIMD -> ~44% true VALU issue duty. BM=32,BN=64 -> 1024 blocks =
// 4 blocks/CU = 4 waves/SIMD. Micro-tile 2x4. Asm uses the "=v" 4-operand
// form that compiled+ran in R2 (tied "+v" form is suspect in the R3/R4
// container failures).

#define BM 32
#define BN 64
#define BK 32
#define LDSA 36  // row stride for As (floats)
#define LDSW 68  // row stride for Ws (floats)

__device__ __forceinline__ void mam_update(float& mx, float& mn, float p0, float p1) {
    float nmx, nmn;
    asm("v_max3_f32 %0, %1, %2, %3" : "=v"(nmx) : "v"(p0), "v"(p1), "v"(mx));
    asm("v_min3_f32 %0, %1, %2, %3" : "=v"(nmn) : "v"(p0), "v"(p1), "v"(mn));
    mx = nmx;
    mn = nmn;
}

__global__ __launch_bounds__(256) void mam_kernel(
    const float* __restrict__ A,
    const float* __restrict__ W,
    const float* __restrict__ bias,
    float* __restrict__ C,
    int M, int N, int K)
{
    __shared__ float As[BK][LDSA];
    __shared__ float Ws[BK][LDSW];

    const int t  = threadIdx.x;
    const int tx = t & 15;   // n micro index (0..15), 4 cols each
    const int ty = t >> 4;   // m micro index (0..15), 2 rows each
    const int m0 = blockIdx.y * BM;
    const int n0 = blockIdx.x * BN;

    const int r  = t >> 3;   // staging row (0..31)
    const int kq = t & 7;    // staging k-quad

    const float* Aptr = A + (size_t)(m0 + r) * K + kq * 4;
    const float* Wptr = W + (size_t)(n0 + r) * K + kq * 4;

    float vmax[2][4], vmin[2][4];
#pragma unroll
    for (int i = 0; i < 2; ++i)
#pragma unroll
        for (int j = 0; j < 4; ++j) {
            vmax[i][j] = -INFINITY;
            vmin[i][j] =  INFINITY;
        }

    for (int k0 = 0; k0 < K; k0 += BK) {
        // stage A: 32x32 tile, one float4 per thread, transposed into LDS
        float4 a0 = *(const float4*)(Aptr);
        // stage W: 64x32 tile, two float4 per thread
        float4 w0 = *(const float4*)(Wptr);
        float4 w1 = *(const float4*)(Wptr + (size_t)32 * K);
        Aptr += BK;
        Wptr += BK;

        const int kk = kq * 4;
        As[kk + 0][r] = a0.x;
        As[kk + 1][r] = a0.y;
        As[kk + 2][r] = a0.z;
        As[kk + 3][r] = a0.w;

        Ws[kk + 0][r]      = w0.x;
        Ws[kk + 1][r]      = w0.y;
        Ws[kk + 2][r]      = w0.z;
        Ws[kk + 3][r]      = w0.w;
        Ws[kk + 0][r + 32] = w1.x;
        Ws[kk + 1][r + 32] = w1.y;
        Ws[kk + 2][r + 32] = w1.z;
        Ws[kk + 3][r + 32] = w1.w;

        __syncthreads();

#pragma unroll
        for (int k = 0; k < BK; k += 2) {
            // A fragments: float2 per k (2 m-rows)
            float2 ta0 = *(const float2*)&As[k    ][ty * 2];
            float2 ta1 = *(const float2*)&As[k + 1][ty * 2];
            // W fragments: float4 per k (4 n-cols)
            float4 tb0 = *(const float4*)&Ws[k    ][tx * 4];
            float4 tb1 = *(const float4*)&Ws[k + 1][tx * 4];

            float a0v[2] = {ta0.x, ta0.y};
            float a1v[2] = {ta1.x, ta1.y};
            float b0v[4] = {tb0.x, tb0.y, tb0.z, tb0.w};
            float b1v[4] = {tb1.x, tb1.y, tb1.z, tb1.w};

#pragma unroll
            for (int i = 0; i < 2; ++i) {
#pragma unroll
                for (int j = 0; j < 4; ++j) {
                    float p0 = a0v[i] * b0v[j];
                    float p1 = a1v[i] * b1v[j];
                    mam_update(vmax[i][j], vmin[i][j], p0, p1);
                }
            }
        }

        __syncthreads();
    }

    float4 bv = *(const float4*)(bias + n0 + tx * 4);
#pragma unroll
    for (int i = 0; i < 2; ++i) {
        float4 o;
        o.x = vmax[i][0] + vmin[i][0] + bv.x;
        o.y = vmax[i][1] + vmin[i][1] + bv.y;
        o.z = vmax[i][2] + vmin[i][2] + bv.z;
        o.w = vmax[i][3] + vmin[i][3] + bv.w;
        *(float4*)(C + (size_t)(m0 + ty * 2 + i) * N + n0 + tx * 4) = o;
    }
}

extern "C" void kernel_launch(void* const* d_in, const int* in_sizes, int n_in,
                              void* d_out, int out_size, void* d_ws, size_t ws_size,
                              hipStream_t stream) {
    const float* x    = (const float*)d_in[0];
    const float* w    = (const float*)d_in[1];
    const float* bias = (const float*)d_in[2];
    float* out = (float*)d_out;

    const int N = in_sizes[2];
    const int K = in_sizes[1] / N;
    const int M = in_sizes[0] / K;

    dim3 grid(N / BN, M / BM);  // (16, 64) = 1024 blocks -> 4 blocks/CU
    dim3 block(256);
    mam_kernel<<<grid, block, 0, stream>>>(x, w, bias, out, M, N, K);
}